// Round 6
// baseline (141.408 us; speedup 1.0000x reference)
//
#include <hip/hip_runtime.h>
#include <hip/hip_fp16.h>

#define NS 512
#define NR 32768
#define NB 1024
#define Q 8                  // r-splits (eighths)
#define NQ (NR / Q)          // 4096 reactions per eighth
#define G 4                  // batches per block
#define NG (NB / G)          // 256 batch groups
#define ELLK 64              // slots per (eighth, species); mean 24 (verified <=64 in R4/R5)

typedef unsigned short u16x8 __attribute__((ext_vector_type(8)));

// ws layout (bytes):
//   pA   float4[NR]          @ 0       (524288)  alpha,beta,gamma,cr_coef
//   pB   float2[NR]          @ 524288  (262144)  fuv_coef, (s1|s2<<16) bits
//   cnt  int[Q*NS]           @ 786432  (16384)
//   perm uint[Q*NS]          @ 802816  (16384)   (s | cnt<<16) sorted desc by cnt
//   ell  u16[Q][NS][ELLK]    @ 819200  (524288)  row-major per species
// total 1,343,488 B

static __device__ __forceinline__ float rfl(float v) {
  return __int_as_float(__builtin_amdgcn_readfirstlane(__float_as_int(v)));
}
static __device__ __forceinline__ unsigned int pkrtz(float a, float b) {
  auto h = __builtin_amdgcn_cvt_pkrtz(a, b);
  return *reinterpret_cast<unsigned int*>(&h);
}

// Merged prep + find_pr + out-zeroing. Grid 1024 = 32 r-blocks x 32 s-blocks.
// Each block: scans 16 incidence rows for its 1024 reactions (pr recovery),
// packs 32 reactions' params, appends their s1/s2 ELL entries, zeroes 2KB of out.
__global__ __launch_bounds__(256) void build(
    const float* __restrict__ inc, const int* __restrict__ msi,
    const float* __restrict__ alpha, const float* __restrict__ beta,
    const float* __restrict__ gam,   const float* __restrict__ crc,
    const float* __restrict__ fvc,
    float4* __restrict__ pA, float2* __restrict__ pB,
    int* __restrict__ cnt, unsigned short* __restrict__ ell,
    float* __restrict__ out) {
  int rblk = blockIdx.x & 31;
  int sblk = blockIdx.x >> 5;
  int t = threadIdx.x;
  int rbase = rblk * 1024 + 4 * t;

  // ---- pr scan over 16 s-rows ----
  int4 a = reinterpret_cast<const int4*>(msi)[rbase >> 1];
  int4 b = reinterpret_cast<const int4*>(msi)[(rbase >> 1) + 1];
  int s1v[4] = {a.x, a.z, b.x, b.z};
  int s2v[4] = {a.y, a.w, b.y, b.w};
  int pr[4] = {-1, -1, -1, -1};
  int s0 = sblk * 16;
#pragma unroll
  for (int ss = 0; ss < 16; ++ss) {
    int s = s0 + ss;
    float4 v = reinterpret_cast<const float4*>(inc)[((size_t)s * NR + rbase) >> 2];
    float vv[4] = {v.x, v.y, v.z, v.w};
#pragma unroll
    for (int j = 0; j < 4; ++j) {
      float c = vv[j] + (float)(s == s1v[j]) + (float)(s == s2v[j]);
      if (c > 0.5f) pr[j] = s;
    }
  }
#pragma unroll
  for (int j = 0; j < 4; ++j) {
    if (pr[j] >= 0) {
      int r = rbase + j;
      int e8 = r >> 12;
      int p = atomicAdd(&cnt[e8 * NS + pr[j]], 1);
      if (p < ELLK)
        ell[((e8 * NS + pr[j]) << 6) + p] = (unsigned short)(r & (NQ - 1));
    }
  }

  // ---- pack duties: 32 reactions per block ----
  if (t < 32) {
    int r = rblk * 1024 + sblk * 32 + t;
    pA[r] = make_float4(alpha[r], beta[r], gam[r], crc[r]);
    int s1 = msi[2 * r], s2 = msi[2 * r + 1];
    pB[r] = make_float2(fvc[r], __int_as_float(s1 | (s2 << 16)));
    int e8 = r >> 12;
    unsigned short neg = (unsigned short)((r & (NQ - 1)) | 0x8000);
    int p1 = atomicAdd(&cnt[e8 * NS + s1], 1);
    if (p1 < ELLK) ell[((e8 * NS + s1) << 6) + p1] = neg;
    int p2 = atomicAdd(&cnt[e8 * NS + s2], 1);
    if (p2 < ELLK) ell[((e8 * NS + s2) << 6) + p2] = neg;
  }

  // ---- zero d_out slice: 128 float4 per block x 1024 blocks = 2 MB ----
  if (t < 128) {
    reinterpret_cast<float4*>(out)[blockIdx.x * 128 + t] =
        make_float4(0.f, 0.f, 0.f, 0.f);
  }
}

// Per-eighth descending count-sort of species -> perm[rank] = s | cnt<<16.
// Makes phase-2 per-wave loop counts nearly uniform.
__global__ __launch_bounds__(512) void balance(
    const int* __restrict__ cnt, unsigned int* __restrict__ perm) {
  __shared__ unsigned short c[NS];
  int e8 = blockIdx.x;
  int t = threadIdx.x;
  int my = cnt[e8 * NS + t];
  my = my < ELLK ? my : ELLK;
  c[t] = (unsigned short)my;
  __syncthreads();
  int rank = 0;
#pragma unroll 8
  for (int s = 0; s < NS; ++s) {
    int cs = c[s];
    rank += (cs > my) || (cs == my && s < t);
  }
  perm[e8 * NS + rank] = (unsigned int)t | ((unsigned int)my << 16);
}

// One block per (batch-group, eighth). 512 threads, 40 KB LDS -> 4 blocks/CU.
__global__ __launch_bounds__(512, 8) void fused(
    const float* __restrict__ ab, const float* __restrict__ temp,
    const float* __restrict__ crr, const float* __restrict__ fvr,
    const float4* __restrict__ pA, const float2* __restrict__ pB,
    const unsigned int* __restrict__ perm, const unsigned short* __restrict__ ell,
    float* __restrict__ out) {
  __shared__ uint2 gL[NQ];       // 32 KB: (half2(g0,g1), half2(g2,g3))
  __shared__ float4 abF[NS];     // 8 KB: {ab_b0, ab_b1, ab_b2, ab_b3}[s]
  int t = threadIdx.x;
  int grp = blockIdx.x & (NG - 1);
  int e8 = blockIdx.x >> 8;
  int b0 = grp, b1 = grp + NG, b2 = grp + 2 * NG, b3 = grp + 3 * NG;
  int rbase = e8 * NQ;

  abF[t] = make_float4(ab[(size_t)b0 * NS + t], ab[(size_t)b1 * NS + t],
                       ab[(size_t)b2 * NS + t], ab[(size_t)b3 * NS + t]);

  float lt[G], mg[G], cb[G], fb[G];
  int bs[G] = {b0, b1, b2, b3};
#pragma unroll
  for (int i = 0; i < G; ++i) {
    float T = rfl(temp[bs[i]]);
    lt[i] = rfl(log2f(T * (1.0f / 300.0f)));
    mg[i] = rfl(-1.4426950408889634f / T);
    cb[i] = rfl(crr[bs[i]]);
    fb[i] = rfl(fvr[bs[i]]);
  }
  __syncthreads();

  // ---- phase 1: rates * factors for 4 batches ----
#pragma unroll 2
  for (int it = 0; it < NQ / 512; ++it) {
    int rl = t + 512 * it;
    int r = rbase + rl;
    float4 a4 = pA[r];
    float2 bb = pB[r];
    int idx = __float_as_int(bb.y);
    float4 u = abF[idx & 0xffff];
    float4 v = abF[idx >> 16];
    float g0 = fmaf(a4.x, exp2f(fmaf(a4.y, lt[0], a4.z * mg[0])),
                    fmaf(a4.w, cb[0], bb.x * fb[0])) * (u.x * v.x);
    float g1 = fmaf(a4.x, exp2f(fmaf(a4.y, lt[1], a4.z * mg[1])),
                    fmaf(a4.w, cb[1], bb.x * fb[1])) * (u.y * v.y);
    float g2 = fmaf(a4.x, exp2f(fmaf(a4.y, lt[2], a4.z * mg[2])),
                    fmaf(a4.w, cb[2], bb.x * fb[2])) * (u.z * v.z);
    float g3 = fmaf(a4.x, exp2f(fmaf(a4.y, lt[3], a4.z * mg[3])),
                    fmaf(a4.w, cb[3], bb.x * fb[3])) * (u.w * v.w);
    gL[rl] = make_uint2(pkrtz(g0, g1), pkrtz(g2, g3));
  }
  __syncthreads();

  // ---- phase 2: gather owned species column, f16 accumulate ----
  unsigned int pc = perm[e8 * NS + t];
  int sp = pc & 0xffff;
  int cs = pc >> 16;
  const unsigned short* row = ell + ((size_t)(e8 * NS + sp) << 6);

  __half2 accA = __float2half2_rn(0.0f);
  __half2 accB = __float2half2_rn(0.0f);

  int kf = cs & ~7;
  for (int k = 0; k < kf; k += 8) {
    u16x8 ev = *reinterpret_cast<const u16x8*>(row + k);
    uint2 g[8];
#pragma unroll
    for (int j = 0; j < 8; ++j) g[j] = gL[ev[j] & (NQ - 1)];
#pragma unroll
    for (int j = 0; j < 8; ++j) {
      unsigned int se = ev[j] & 0x8000u;
      se |= se << 16;
      unsigned int w0 = g[j].x ^ se, w1 = g[j].y ^ se;
      accA = __hadd2(accA, *reinterpret_cast<__half2*>(&w0));
      accB = __hadd2(accB, *reinterpret_cast<__half2*>(&w1));
    }
  }
  if (cs & 7) {
    u16x8 ev = *reinterpret_cast<const u16x8*>(row + kf);
    uint2 g[8];
#pragma unroll
    for (int j = 0; j < 8; ++j) g[j] = gL[ev[j] & (NQ - 1)];
#pragma unroll
    for (int j = 0; j < 8; ++j) {
      unsigned int se = ev[j] & 0x8000u;
      se |= se << 16;
      unsigned int w0 = g[j].x ^ se, w1 = g[j].y ^ se;
      bool valid = (kf + j) < cs;
      w0 = valid ? w0 : 0u;
      w1 = valid ? w1 : 0u;
      accA = __hadd2(accA, *reinterpret_cast<__half2*>(&w0));
      accB = __hadd2(accB, *reinterpret_cast<__half2*>(&w1));
    }
  }

  float2 fA = __half22float2(accA);
  float2 fB = __half22float2(accB);
  unsafeAtomicAdd(&out[(size_t)b0 * NS + sp], fA.x);
  unsafeAtomicAdd(&out[(size_t)b1 * NS + sp], fA.y);
  unsafeAtomicAdd(&out[(size_t)b2 * NS + sp], fB.x);
  unsafeAtomicAdd(&out[(size_t)b3 * NS + sp], fB.y);
}

extern "C" void kernel_launch(void* const* d_in, const int* in_sizes, int n_in,
                              void* d_out, int out_size, void* d_ws, size_t ws_size,
                              hipStream_t stream) {
  const float* ab    = (const float*)d_in[1];
  const float* temp  = (const float*)d_in[2];
  const float* crr   = (const float*)d_in[3];
  const float* fvr   = (const float*)d_in[4];
  const float* inc   = (const float*)d_in[5];
  const float* alpha = (const float*)d_in[6];
  const float* beta  = (const float*)d_in[7];
  const float* gam   = (const float*)d_in[8];
  const float* crc   = (const float*)d_in[9];
  const float* fvc   = (const float*)d_in[10];
  const int*   msi   = (const int*)d_in[12];

  char* ws = (char*)d_ws;
  float4* pA           = (float4*)(ws);
  float2* pB           = (float2*)(ws + 524288);
  int* cnt             = (int*)(ws + 786432);
  unsigned int* perm   = (unsigned int*)(ws + 802816);
  unsigned short* ellp = (unsigned short*)(ws + 819200);
  float* out = (float*)d_out;

  hipMemsetAsync(cnt, 0, Q * NS * sizeof(int), stream);
  build<<<1024, 256, 0, stream>>>(inc, msi, alpha, beta, gam, crc, fvc,
                                  pA, pB, cnt, ellp, out);
  balance<<<Q, 512, 0, stream>>>(cnt, perm);
  fused<<<NG * Q, 512, 0, stream>>>(ab, temp, crr, fvr, pA, pB, perm, ellp, out);
}

// Round 7
// 74.358 us; speedup vs baseline: 1.9017x; 1.9017x over previous
//
#include <hip/hip_runtime.h>
#include <hip/hip_fp16.h>

#define NS 512
#define NR 32768
#define NB 1024
#define Q 8                  // r-splits (eighths)
#define NQ (NR / Q)          // 4096 reactions per eighth
#define G 4                  // batches per block
#define NG (NB / G)          // 256 batch groups
#define ELLK 64              // slots per (eighth, species); mean 24 (verified <=64 in R4/R5)

typedef unsigned short u16x8 __attribute__((ext_vector_type(8)));

// ws layout (bytes):
//   pA   float4[NR]          @ 0       (524288)  alpha,beta,gamma,cr_coef
//   pB   float2[NR]          @ 524288  (262144)  fuv_coef, (s1|s2<<16) bits
//   cnt  int[Q*NS]           @ 786432  (16384)
//   perm uint[Q*NS]          @ 802816  (16384)   (s | cnt<<16) sorted desc by cnt
//   ell  u16[Q][NS][ELLK]    @ 819200  (524288)  row-major per species
// total 1,343,488 B

static __device__ __forceinline__ float rfl(float v) {
  return __int_as_float(__builtin_amdgcn_readfirstlane(__float_as_int(v)));
}
static __device__ __forceinline__ unsigned int pkrtz(float a, float b) {
  auto h = __builtin_amdgcn_cvt_pkrtz(a, b);
  return *reinterpret_cast<unsigned int*>(&h);
}

// Merged prep + find_pr + out-zeroing. Grid 1024 = 32 r-blocks x 32 s-blocks.
__global__ __launch_bounds__(256) void build(
    const float* __restrict__ inc, const int* __restrict__ msi,
    const float* __restrict__ alpha, const float* __restrict__ beta,
    const float* __restrict__ gam,   const float* __restrict__ crc,
    const float* __restrict__ fvc,
    float4* __restrict__ pA, float2* __restrict__ pB,
    int* __restrict__ cnt, unsigned short* __restrict__ ell,
    float* __restrict__ out) {
  int rblk = blockIdx.x & 31;
  int sblk = blockIdx.x >> 5;
  int t = threadIdx.x;
  int rbase = rblk * 1024 + 4 * t;

  // ---- pr scan over 16 s-rows ----
  int4 a = reinterpret_cast<const int4*>(msi)[rbase >> 1];
  int4 b = reinterpret_cast<const int4*>(msi)[(rbase >> 1) + 1];
  int s1v[4] = {a.x, a.z, b.x, b.z};
  int s2v[4] = {a.y, a.w, b.y, b.w};
  int pr[4] = {-1, -1, -1, -1};
  int s0 = sblk * 16;
#pragma unroll
  for (int ss = 0; ss < 16; ++ss) {
    int s = s0 + ss;
    float4 v = reinterpret_cast<const float4*>(inc)[((size_t)s * NR + rbase) >> 2];
    float vv[4] = {v.x, v.y, v.z, v.w};
#pragma unroll
    for (int j = 0; j < 4; ++j) {
      float c = vv[j] + (float)(s == s1v[j]) + (float)(s == s2v[j]);
      if (c > 0.5f) pr[j] = s;
    }
  }
#pragma unroll
  for (int j = 0; j < 4; ++j) {
    if (pr[j] >= 0) {
      int r = rbase + j;
      int e8 = r >> 12;
      int p = atomicAdd(&cnt[e8 * NS + pr[j]], 1);
      if (p < ELLK)
        ell[((e8 * NS + pr[j]) << 6) + p] = (unsigned short)(r & (NQ - 1));
    }
  }

  // ---- pack duties: 32 reactions per block ----
  if (t < 32) {
    int r = rblk * 1024 + sblk * 32 + t;
    pA[r] = make_float4(alpha[r], beta[r], gam[r], crc[r]);
    int s1 = msi[2 * r], s2 = msi[2 * r + 1];
    pB[r] = make_float2(fvc[r], __int_as_float(s1 | (s2 << 16)));
    int e8 = r >> 12;
    unsigned short neg = (unsigned short)((r & (NQ - 1)) | 0x8000);
    int p1 = atomicAdd(&cnt[e8 * NS + s1], 1);
    if (p1 < ELLK) ell[((e8 * NS + s1) << 6) + p1] = neg;
    int p2 = atomicAdd(&cnt[e8 * NS + s2], 1);
    if (p2 < ELLK) ell[((e8 * NS + s2) << 6) + p2] = neg;
  }

  // ---- zero d_out slice ----
  if (t < 128) {
    reinterpret_cast<float4*>(out)[blockIdx.x * 128 + t] =
        make_float4(0.f, 0.f, 0.f, 0.f);
  }
}

// Per-eighth descending count-sort of species -> perm[rank] = s | cnt<<16.
__global__ __launch_bounds__(512) void balance(
    const int* __restrict__ cnt, unsigned int* __restrict__ perm) {
  __shared__ unsigned short c[NS];
  int e8 = blockIdx.x;
  int t = threadIdx.x;
  int my = cnt[e8 * NS + t];
  my = my < ELLK ? my : ELLK;
  c[t] = (unsigned short)my;
  __syncthreads();
  int rank = 0;
#pragma unroll 8
  for (int s = 0; s < NS; ++s) {
    int cs = c[s];
    rank += (cs > my) || (cs == my && s < t);
  }
  perm[e8 * NS + rank] = (unsigned int)t | ((unsigned int)my << 16);
}

// One block per (batch-group, eighth). 512 threads, 40 KB LDS -> 4 blocks/CU.
__global__ __launch_bounds__(512, 8) void fused(
    const float* __restrict__ ab, const float* __restrict__ temp,
    const float* __restrict__ crr, const float* __restrict__ fvr,
    const float4* __restrict__ pA, const float2* __restrict__ pB,
    const unsigned int* __restrict__ perm, const unsigned short* __restrict__ ell,
    float* __restrict__ out) {
  __shared__ uint2 gL[NQ];       // 32 KB: (half2(g0,g1), half2(g2,g3))
  __shared__ float4 abF[NS];     // 8 KB: phase1 = ab table; phase2 = output stage
  int t = threadIdx.x;
  int grp = blockIdx.x & (NG - 1);
  int e8 = blockIdx.x >> 8;
  int b0 = grp, b1 = grp + NG, b2 = grp + 2 * NG, b3 = grp + 3 * NG;
  int rbase = e8 * NQ;

  abF[t] = make_float4(ab[(size_t)b0 * NS + t], ab[(size_t)b1 * NS + t],
                       ab[(size_t)b2 * NS + t], ab[(size_t)b3 * NS + t]);

  float lt[G], mg[G], cb[G], fb[G];
  int bs[G] = {b0, b1, b2, b3};
#pragma unroll
  for (int i = 0; i < G; ++i) {
    float T = rfl(temp[bs[i]]);
    lt[i] = rfl(log2f(T * (1.0f / 300.0f)));
    mg[i] = rfl(-1.4426950408889634f / T);
    cb[i] = rfl(crr[bs[i]]);
    fb[i] = rfl(fvr[bs[i]]);
  }
  __syncthreads();

  // ---- phase 1: rates * factors for 4 batches ----
#pragma unroll 2
  for (int it = 0; it < NQ / 512; ++it) {
    int rl = t + 512 * it;
    int r = rbase + rl;
    float4 a4 = pA[r];
    float2 bb = pB[r];
    int idx = __float_as_int(bb.y);
    float4 u = abF[idx & 0xffff];
    float4 v = abF[idx >> 16];
    float g0 = fmaf(a4.x, exp2f(fmaf(a4.y, lt[0], a4.z * mg[0])),
                    fmaf(a4.w, cb[0], bb.x * fb[0])) * (u.x * v.x);
    float g1 = fmaf(a4.x, exp2f(fmaf(a4.y, lt[1], a4.z * mg[1])),
                    fmaf(a4.w, cb[1], bb.x * fb[1])) * (u.y * v.y);
    float g2 = fmaf(a4.x, exp2f(fmaf(a4.y, lt[2], a4.z * mg[2])),
                    fmaf(a4.w, cb[2], bb.x * fb[2])) * (u.z * v.z);
    float g3 = fmaf(a4.x, exp2f(fmaf(a4.y, lt[3], a4.z * mg[3])),
                    fmaf(a4.w, cb[3], bb.x * fb[3])) * (u.w * v.w);
    gL[rl] = make_uint2(pkrtz(g0, g1), pkrtz(g2, g3));
  }
  __syncthreads();

  // ---- phase 2: gather owned (rank-balanced) species column, f16 accumulate ----
  unsigned int pc = perm[e8 * NS + t];
  int sp = pc & 0xffff;
  int cs = pc >> 16;
  const unsigned short* row = ell + ((size_t)(e8 * NS + sp) << 6);

  __half2 accA = __float2half2_rn(0.0f);
  __half2 accB = __float2half2_rn(0.0f);

  int kf = cs & ~7;
  for (int k = 0; k < kf; k += 8) {
    u16x8 ev = *reinterpret_cast<const u16x8*>(row + k);
    uint2 g[8];
#pragma unroll
    for (int j = 0; j < 8; ++j) g[j] = gL[ev[j] & (NQ - 1)];
#pragma unroll
    for (int j = 0; j < 8; ++j) {
      unsigned int se = ev[j] & 0x8000u;
      se |= se << 16;
      unsigned int w0 = g[j].x ^ se, w1 = g[j].y ^ se;
      accA = __hadd2(accA, *reinterpret_cast<__half2*>(&w0));
      accB = __hadd2(accB, *reinterpret_cast<__half2*>(&w1));
    }
  }
  if (cs & 7) {
    u16x8 ev = *reinterpret_cast<const u16x8*>(row + kf);
    uint2 g[8];
#pragma unroll
    for (int j = 0; j < 8; ++j) g[j] = gL[ev[j] & (NQ - 1)];
#pragma unroll
    for (int j = 0; j < 8; ++j) {
      unsigned int se = ev[j] & 0x8000u;
      se |= se << 16;
      unsigned int w0 = g[j].x ^ se, w1 = g[j].y ^ se;
      bool valid = (kf + j) < cs;
      w0 = valid ? w0 : 0u;
      w1 = valid ? w1 : 0u;
      accA = __hadd2(accA, *reinterpret_cast<__half2*>(&w0));
      accB = __hadd2(accB, *reinterpret_cast<__half2*>(&w1));
    }
  }

  // ---- de-permute through LDS, then coalesced global atomics ----
  float2 fA = __half22float2(accA);
  float2 fB = __half22float2(accB);
  __syncthreads();                       // abF's phase-1 role is over
  abF[sp] = make_float4(fA.x, fA.y, fB.x, fB.y);
  __syncthreads();
  float4 o = abF[t];
  unsafeAtomicAdd(&out[(size_t)b0 * NS + t], o.x);
  unsafeAtomicAdd(&out[(size_t)b1 * NS + t], o.y);
  unsafeAtomicAdd(&out[(size_t)b2 * NS + t], o.z);
  unsafeAtomicAdd(&out[(size_t)b3 * NS + t], o.w);
}

extern "C" void kernel_launch(void* const* d_in, const int* in_sizes, int n_in,
                              void* d_out, int out_size, void* d_ws, size_t ws_size,
                              hipStream_t stream) {
  const float* ab    = (const float*)d_in[1];
  const float* temp  = (const float*)d_in[2];
  const float* crr   = (const float*)d_in[3];
  const float* fvr   = (const float*)d_in[4];
  const float* inc   = (const float*)d_in[5];
  const float* alpha = (const float*)d_in[6];
  const float* beta  = (const float*)d_in[7];
  const float* gam   = (const float*)d_in[8];
  const float* crc   = (const float*)d_in[9];
  const float* fvc   = (const float*)d_in[10];
  const int*   msi   = (const int*)d_in[12];

  char* ws = (char*)d_ws;
  float4* pA           = (float4*)(ws);
  float2* pB           = (float2*)(ws + 524288);
  int* cnt             = (int*)(ws + 786432);
  unsigned int* perm   = (unsigned int*)(ws + 802816);
  unsigned short* ellp = (unsigned short*)(ws + 819200);
  float* out = (float*)d_out;

  hipMemsetAsync(cnt, 0, Q * NS * sizeof(int), stream);
  build<<<1024, 256, 0, stream>>>(inc, msi, alpha, beta, gam, crc, fvc,
                                  pA, pB, cnt, ellp, out);
  balance<<<Q, 512, 0, stream>>>(cnt, perm);
  fused<<<NG * Q, 512, 0, stream>>>(ab, temp, crr, fvr, pA, pB, perm, ellp, out);
}